// Round 1
// baseline (543.527 us; speedup 1.0000x reference)
//
#include <hip/hip_runtime.h>

#define N_ROWS 65536
#define DIM    256
#define KCODES 1024

#define TM 128
#define TN 128
#define DK 32
#define LPAD 132   // padded leading dim (multiple of 4 for float4-aligned rows; +4 breaks bank stride)

struct Partial { float v; int i; };

// ---------------- kernel 1: row norms (z_e) and code norms (codebook) ----------------
__global__ __launch_bounds__(256) void vq_norms(const float* __restrict__ z,
                                                const float* __restrict__ cb,
                                                float* __restrict__ rowN,
                                                float* __restrict__ codeN) {
    int wave = (int)((blockIdx.x * 256u + threadIdx.x) >> 6);
    int lane = threadIdx.x & 63;
    const float* src;
    float* dst;
    if (wave < N_ROWS) { src = z  + (size_t)wave * DIM;            dst = rowN  + wave; }
    else               { int c = wave - N_ROWS;
                         src = cb + (size_t)c * DIM;               dst = codeN + c;    }
    float4 v = ((const float4*)src)[lane];
    float s = v.x*v.x + v.y*v.y + v.z*v.z + v.w*v.w;
    #pragma unroll
    for (int m = 32; m; m >>= 1) s += __shfl_xor(s, m, 64);
    if (lane == 0) *dst = s;
}

// ---------------- kernel 2: fp32 GEMM tile + fused partial argmin ----------------
// grid: 4096 blocks; rtile fastest so concurrently-dispatched blocks read distinct A panels.
__global__ __launch_bounds__(256) void vq_gemm(const float* __restrict__ A,
                                               const float* __restrict__ B,
                                               const float* __restrict__ rowN,
                                               const float* __restrict__ codeN,
                                               Partial* __restrict__ part) {
    __shared__ float Al[DK][LPAD];
    __shared__ float Bl[DK][LPAD];

    int bid   = blockIdx.x;
    int ctile = bid >> 9;     // 0..7
    int rtile = bid & 511;    // 0..511
    int tid   = threadIdx.x;
    int tx    = tid & 15;     // code group
    int ty    = tid >> 4;     // row group

    float acc[8][8];
    #pragma unroll
    for (int i = 0; i < 8; ++i)
        #pragma unroll
        for (int j = 0; j < 8; ++j) acc[i][j] = 0.f;

    const float* Abase = A + (size_t)rtile * TM * DIM;
    const float* Bbase = B + (size_t)ctile * TN * DIM;

    for (int ds = 0; ds < DIM / DK; ++ds) {
        int d0 = ds * DK;
        __syncthreads();
        // stage transposed tiles: Al[d][row], Bl[d][code]
        #pragma unroll
        for (int it = 0; it < 4; ++it) {
            int f   = it * 256 + tid;     // 0..1023 float4 slots
            int row = f >> 3;             // 0..127
            int dc  = (f & 7) << 2;       // 0,4,...,28
            float4 va = *(const float4*)(Abase + (size_t)row * DIM + d0 + dc);
            Al[dc + 0][row] = va.x; Al[dc + 1][row] = va.y;
            Al[dc + 2][row] = va.z; Al[dc + 3][row] = va.w;
            float4 vb = *(const float4*)(Bbase + (size_t)row * DIM + d0 + dc);
            Bl[dc + 0][row] = vb.x; Bl[dc + 1][row] = vb.y;
            Bl[dc + 2][row] = vb.z; Bl[dc + 3][row] = vb.w;
        }
        __syncthreads();

        #pragma unroll 4
        for (int d = 0; d < DK; ++d) {
            const float4 a0 = *(const float4*)&Al[d][ty * 8];
            const float4 a1 = *(const float4*)&Al[d][ty * 8 + 4];
            const float4 b0 = *(const float4*)&Bl[d][tx * 8];
            const float4 b1 = *(const float4*)&Bl[d][tx * 8 + 4];
            float a[8] = {a0.x, a0.y, a0.z, a0.w, a1.x, a1.y, a1.z, a1.w};
            float b[8] = {b0.x, b0.y, b0.z, b0.w, b1.x, b1.y, b1.z, b1.w};
            #pragma unroll
            for (int i = 0; i < 8; ++i)
                #pragma unroll
                for (int j = 0; j < 8; ++j)
                    acc[i][j] = fmaf(a[i], b[j], acc[i][j]);
        }
    }

    // epilogue: dists replicating reference rounding: (rowN + codeN) - 2*dot
    float rn[8], cn[8];
    #pragma unroll
    for (int i = 0; i < 8; ++i) rn[i] = rowN[rtile * TM + ty * 8 + i];
    #pragma unroll
    for (int j = 0; j < 8; ++j) cn[j] = codeN[ctile * TN + tx * 8 + j];

    #pragma unroll
    for (int i = 0; i < 8; ++i) {
        float bv = 3.402823466e+38f;
        int   bi = 0x7fffffff;
        #pragma unroll
        for (int j = 0; j < 8; ++j) {
            float t1 = rn[i] + cn[j];
            float dv = t1 - 2.0f * acc[i][j];
            if (dv < bv) { bv = dv; bi = ctile * TN + tx * 8 + j; }
        }
        // reduce across the 16 tx lanes (same row), tie -> lower code index
        #pragma unroll
        for (int m = 1; m <= 8; m <<= 1) {
            float ov = __shfl_xor(bv, m, 64);
            int   oi = __shfl_xor(bi, m, 64);
            if (ov < bv || (ov == bv && oi < bi)) { bv = ov; bi = oi; }
        }
        if (tx == 0) {
            int row = rtile * TM + ty * 8 + i;
            Partial p; p.v = bv; p.i = bi;
            part[(row << 3) + ctile] = p;
        }
    }
}

// ---------------- kernel 3: reduce partials, gather z_q, histogram ----------------
__global__ __launch_bounds__(256) void vq_reduce(const float* __restrict__ cb,
                                                 const Partial* __restrict__ part,
                                                 int* __restrict__ hist,
                                                 float* __restrict__ zq) {
    int row  = (int)((blockIdx.x * 256u + threadIdx.x) >> 6);
    int lane = threadIdx.x & 63;
    float bv = 3.402823466e+38f;
    int   bi = 0x7fffffff;
    if (lane < 8) { Partial p = part[(row << 3) + lane]; bv = p.v; bi = p.i; }
    #pragma unroll
    for (int m = 1; m <= 4; m <<= 1) {
        float ov = __shfl_xor(bv, m, 64);
        int   oi = __shfl_xor(bi, m, 64);
        if (ov < bv || (ov == bv && oi < bi)) { bv = ov; bi = oi; }
    }
    bi = __shfl(bi, 0, 64);
    float4 v = ((const float4*)(cb + (size_t)bi * DIM))[lane];
    ((float4*)(zq + (size_t)row * DIM))[lane] = v;
    if (lane == 0) atomicAdd(&hist[bi], 1);
}

// ---------------- kernel 4: perplexity ----------------
__global__ __launch_bounds__(256) void vq_perp(const int* __restrict__ hist,
                                               float* __restrict__ out) {
    __shared__ float red[4];
    int tid = threadIdx.x;
    float s = 0.f;
    #pragma unroll
    for (int k = tid; k < KCODES; k += 256) {
        float avg = (float)hist[k] * (1.0f / 65536.0f);
        s += avg * logf(avg + 1e-10f);
    }
    #pragma unroll
    for (int m = 32; m; m >>= 1) s += __shfl_xor(s, m, 64);
    if ((tid & 63) == 0) red[tid >> 6] = s;
    __syncthreads();
    if (tid == 0) out[0] = expf(-(red[0] + red[1] + red[2] + red[3]));
}

// ---------------- launch ----------------
extern "C" void kernel_launch(void* const* d_in, const int* in_sizes, int n_in,
                              void* d_out, int out_size, void* d_ws, size_t ws_size,
                              hipStream_t stream) {
    const float* z  = (const float*)d_in[0];
    const float* cb = (const float*)d_in[1];

    float*   rowN  = (float*)d_ws;                       // 65536 f32
    float*   codeN = rowN + N_ROWS;                      // 1024 f32
    int*     hist  = (int*)(codeN + KCODES);             // 1024 i32
    Partial* part  = (Partial*)((char*)d_ws + 270336);   // 65536*8 Partial (4 MB), 8B aligned

    float* zq   = (float*)d_out;
    float* perp = zq + (size_t)N_ROWS * DIM;

    hipMemsetAsync(hist, 0, KCODES * sizeof(int), stream);
    vq_norms <<<16640, 256, 0, stream>>>(z, cb, rowN, codeN);
    vq_gemm  <<<4096,  256, 0, stream>>>(z, cb, rowN, codeN, part);
    vq_reduce<<<16384, 256, 0, stream>>>(cb, part, hist, zq);
    vq_perp  <<<1,     256, 0, stream>>>(hist, perp);
}

// Round 2
// 497.797 us; speedup vs baseline: 1.0919x; 1.0919x over previous
//
#include <hip/hip_runtime.h>

#define N_ROWS 65536
#define DIM    256
#define KCODES 1024
#define FLTMAX 3.402823466e+38f

typedef short short8 __attribute__((ext_vector_type(8)));
typedef float f32x4  __attribute__((ext_vector_type(4)));
typedef unsigned short ushort_t;

struct Partial { float v; int i; };

__device__ __forceinline__ void gll16(const void* g, void* l) {
    __builtin_amdgcn_global_load_lds((const __attribute__((address_space(1))) void*)g,
                                     (__attribute__((address_space(3))) void*)l, 16, 0, 0);
}

__device__ __forceinline__ ushort_t bf16rn(float a) {
    unsigned ub = __float_as_uint(a);
    return (ushort_t)((ub + 0x7fffu + ((ub >> 16) & 1u)) >> 16);
}

// ============ kernel 1: norms + bf16 hi/lo split prep ============
// rows 0..65535 -> z/A2/rn ; rows 65536..66559 -> cb/B2/cn
__global__ __launch_bounds__(256) void vq_prep(const float* __restrict__ z,
                                               const float* __restrict__ cbk,
                                               ushort_t* __restrict__ A2,
                                               ushort_t* __restrict__ B2,
                                               float* __restrict__ rn,
                                               float* __restrict__ cn) {
    int gid = blockIdx.x * 256 + threadIdx.x;
    int row = gid >> 6;
    int l   = gid & 63;
    const float* src; ushort_t* dst; float* ndst;
    if (row < N_ROWS) { src = z   + (size_t)row * DIM; dst = A2 + (size_t)row * 512; ndst = rn + row; }
    else { int c = row - N_ROWS; src = cbk + (size_t)c * DIM; dst = B2 + (size_t)c * 512; ndst = cn + c; }
    float4 v = ((const float4*)src)[l];
    float s = v.x*v.x + v.y*v.y + v.z*v.z + v.w*v.w;
    #pragma unroll
    for (int m = 32; m; m >>= 1) s += __shfl_xor(s, m, 64);
    if (l == 0) *ndst = s;
    float a[4] = {v.x, v.y, v.z, v.w};
    ushort_t hi[4], lo[4];
    #pragma unroll
    for (int j = 0; j < 4; ++j) {
        hi[j] = bf16rn(a[j]);
        float r = a[j] - __uint_as_float(((unsigned)hi[j]) << 16);
        lo[j] = bf16rn(r);
    }
    ushort4 H = {hi[0], hi[1], hi[2], hi[3]};
    ushort4 L = {lo[0], lo[1], lo[2], lo[3]};
    *(ushort4*)(dst + l * 4)       = H;   // hi at k 0..255
    *(ushort4*)(dst + 256 + l * 4) = L;   // lo at k 256..511
}

// ============ kernel 2: bf16x3-split MFMA GEMM + fused top-2 argmin ============
// 128x128 tile, BK=64, K'=768 via segment map (hi*hi, hi*lo, lo*hi).
__global__ __launch_bounds__(256) void vq_gemm2(const ushort_t* __restrict__ A2,
                                                const ushort_t* __restrict__ B2,
                                                const float* __restrict__ rn,
                                                const float* __restrict__ cn,
                                                float4* __restrict__ part) {
    __shared__ __align__(16) ushort_t As[128 * 64];
    __shared__ __align__(16) ushort_t Bs[128 * 64];

    int bid = blockIdx.x;
    // XCD-aware: ctile fast within each XCD's stream -> A panel L2-reuse
    int ctile = (bid >> 3) & 7;
    int rtile = (bid & 7) | ((bid >> 6) << 3);
    int tid = threadIdx.x;
    int wid = tid >> 6;
    int l   = tid & 63;
    int li  = l & 15, lg = l >> 4;
    int lrow  = l >> 3;                    // staging: row within 8-row chunk
    int lcolb = ((l & 7) ^ lrow) << 4;     // pre-swizzled source byte column
    int swz   = (l & 7) << 4;              // read-side swizzle

    const size_t arow0 = (size_t)rtile * 128;
    const size_t ccol0 = (size_t)ctile * 128;

    f32x4 acc[2][8];
    #pragma unroll
    for (int rt = 0; rt < 2; ++rt)
        #pragma unroll
        for (int ct = 0; ct < 8; ++ct) acc[rt][ct] = (f32x4)0.f;

    // precompute frag LDS byte offsets (static arrays, fully unrolled access)
    int aO[2][2], bO[8][2];
    #pragma unroll
    for (int rt = 0; rt < 2; ++rt)
        #pragma unroll
        for (int ks = 0; ks < 2; ++ks)
            aO[rt][ks] = (wid*32 + rt*16 + li) * 128 + ((ks*64 + lg*16) ^ swz);
    #pragma unroll
    for (int ct = 0; ct < 8; ++ct)
        #pragma unroll
        for (int ks = 0; ks < 2; ++ks)
            bO[ct][ks] = (ct*16 + li) * 128 + ((ks*64 + lg*16) ^ swz);

    const char* gb; char* lb;
    int wrow0 = (wid & 1) * 64;
    if (wid < 2) { gb = (const char*)A2 + arow0 * 1024; lb = (char*)As; }
    else         { gb = (const char*)B2 + ccol0 * 1024; lb = (char*)Bs; }

    for (int s = 0; s < 12; ++s) {
        int aoff2 = (s < 8 ? (s & 3) * 64 : 256 + (s & 3) * 64) * 2;
        int boff2 = (s < 4 ? s * 64 : (s < 8 ? 256 + (s & 3) * 64 : (s & 3) * 64)) * 2;
        int off2 = (wid < 2) ? aoff2 : boff2;
        #pragma unroll
        for (int jj = 0; jj < 8; ++jj) {
            int r = wrow0 + jj * 8 + lrow;
            gll16(gb + (size_t)r * 1024 + off2 + lcolb,
                  lb + (wrow0 + jj * 8) * 128 + l * 16);
        }
        __syncthreads();
        #pragma unroll
        for (int ks = 0; ks < 2; ++ks) {
            short8 af[2];
            #pragma unroll
            for (int rt = 0; rt < 2; ++rt)
                af[rt] = *(const short8*)((const char*)As + aO[rt][ks]);
            #pragma unroll
            for (int ct = 0; ct < 8; ++ct) {
                short8 bf = *(const short8*)((const char*)Bs + bO[ct][ks]);
                acc[0][ct] = __builtin_amdgcn_mfma_f32_16x16x32_bf16(af[0], bf, acc[0][ct], 0, 0, 0);
                acc[1][ct] = __builtin_amdgcn_mfma_f32_16x16x32_bf16(af[1], bf, acc[1][ct], 0, 0, 0);
            }
        }
        __syncthreads();
    }

    // epilogue: dist = (rn + cn) - 2*dot ; per-row top-2 over this block's 128 codes
    float cnv[8];
    #pragma unroll
    for (int ct = 0; ct < 8; ++ct) cnv[ct] = cn[ccol0 + ct*16 + li];

    #pragma unroll
    for (int rt = 0; rt < 2; ++rt) {
        #pragma unroll
        for (int q = 0; q < 4; ++q) {
            int rowl = wid*32 + rt*16 + lg*4 + q;
            float rv = rn[arow0 + rowl];
            float v1 = FLTMAX; int i1 = 0x7fffffff;
            float v2 = FLTMAX; int i2 = 0x7fffffff;
            #pragma unroll
            for (int ct = 0; ct < 8; ++ct) {
                float dv = (rv + cnv[ct]) - 2.0f * acc[rt][ct][q];
                int  di = (int)ccol0 + ct*16 + li;
                bool b1 = (dv < v1) || (dv == v1 && di < i1);
                bool b2 = (dv < v2) || (dv == v2 && di < i2);
                float ov1 = v1; int oi1 = i1;
                if (b1)      { v1 = dv; i1 = di; v2 = ov1; i2 = oi1; }
                else if (b2) { v2 = dv; i2 = di; }
            }
            #pragma unroll
            for (int m = 1; m <= 8; m <<= 1) {
                float w1 = __shfl_xor(v1, m, 64); int j1 = __shfl_xor(i1, m, 64);
                float w2 = __shfl_xor(v2, m, 64); int j2 = __shfl_xor(i2, m, 64);
                bool first = (w1 < v1) || (w1 == v1 && j1 < i1);
                float nv1 = first ? w1 : v1; int ni1 = first ? j1 : i1;
                float c2v = first ? v1 : w1; int c2i = first ? i1 : j1;
                float av2 = first ? w2 : v2; int ai2 = first ? j2 : i2;
                bool s2 = (av2 < c2v) || (av2 == c2v && ai2 < c2i);
                v1 = nv1; i1 = ni1;
                v2 = s2 ? av2 : c2v; i2 = s2 ? ai2 : c2i;
            }
            if (li == 0) {
                float4 o;
                o.x = v1; o.y = __int_as_float(i1);
                o.z = v2; o.w = __int_as_float(i2);
                part[(arow0 + rowl) * 8 + ctile] = o;
            }
        }
    }
}

// ============ kernel 3: exact refinement + gather + histogram ============
__global__ __launch_bounds__(256) void vq_refine(const float* __restrict__ z,
                                                 const float* __restrict__ cbk,
                                                 const float* __restrict__ rn,
                                                 const float* __restrict__ cn,
                                                 const float4* __restrict__ part,
                                                 int* __restrict__ hist,
                                                 float* __restrict__ zq) {
    int gid = blockIdx.x * 256 + threadIdx.x;
    int row = gid >> 6;
    int l   = gid & 63;
    float vc = FLTMAX; int ic = 0x7fffffff;
    if (l < 16) {
        float4 P = part[(size_t)row * 8 + (l & 7)];
        if (l < 8) { vc = P.x; ic = __float_as_int(P.y); }
        else       { vc = P.z; ic = __float_as_int(P.w); }
    }
    float vmin = vc;
    #pragma unroll
    for (int m = 1; m <= 8; m <<= 1) vmin = fminf(vmin, __shfl_xor(vmin, m, 64));

    float dv = FLTMAX; int ci = 0x7fffffff;
    if (l < 16 && vc <= vmin + 2e-4f) {
        float dot = 0.f;
        const float* zr = z   + (size_t)row * DIM;
        const float* cr = cbk + (size_t)ic * DIM;
        #pragma unroll 32
        for (int d = 0; d < DIM; ++d) dot = fmaf(zr[d], cr[d], dot);  // sequential-d: matches R1-exact order
        float t1 = rn[row] + cn[ic];
        dv = t1 - 2.0f * dot;
        ci = ic;
    }
    #pragma unroll
    for (int m = 1; m <= 8; m <<= 1) {
        float ov = __shfl_xor(dv, m, 64); int oi = __shfl_xor(ci, m, 64);
        if (ov < dv || (ov == dv && oi < ci)) { dv = ov; ci = oi; }
    }
    int bi = __shfl(ci, 0, 64);
    float4 v = ((const float4*)(cbk + (size_t)bi * DIM))[l];
    ((float4*)(zq + (size_t)row * DIM))[l] = v;
    if (l == 0) atomicAdd(hist + bi, 1);
}

// ============ kernel 4: perplexity (identical to R1) ============
__global__ __launch_bounds__(256) void vq_perp(const int* __restrict__ hist,
                                               float* __restrict__ out) {
    __shared__ float red[4];
    int tid = threadIdx.x;
    float s = 0.f;
    #pragma unroll
    for (int k = tid; k < KCODES; k += 256) {
        float avg = (float)hist[k] * (1.0f / 65536.0f);
        s += avg * logf(avg + 1e-10f);
    }
    #pragma unroll
    for (int m = 32; m; m >>= 1) s += __shfl_xor(s, m, 64);
    if ((tid & 63) == 0) red[tid >> 6] = s;
    __syncthreads();
    if (tid == 0) out[0] = expf(-(red[0] + red[1] + red[2] + red[3]));
}

// ============ R1 fallback kernels (used only if ws_size too small) ============
__global__ __launch_bounds__(256) void vq_norms(const float* __restrict__ z,
                                                const float* __restrict__ cb,
                                                float* __restrict__ rowN,
                                                float* __restrict__ codeN) {
    int wave = (int)((blockIdx.x * 256u + threadIdx.x) >> 6);
    int lane = threadIdx.x & 63;
    const float* src; float* dst;
    if (wave < N_ROWS) { src = z + (size_t)wave * DIM; dst = rowN + wave; }
    else { int c = wave - N_ROWS; src = cb + (size_t)c * DIM; dst = codeN + c; }
    float4 v = ((const float4*)src)[lane];
    float s = v.x*v.x + v.y*v.y + v.z*v.z + v.w*v.w;
    #pragma unroll
    for (int m = 32; m; m >>= 1) s += __shfl_xor(s, m, 64);
    if (lane == 0) *dst = s;
}

__global__ __launch_bounds__(256) void vq_gemm_f32(const float* __restrict__ A,
                                                   const float* __restrict__ B,
                                                   const float* __restrict__ rowN,
                                                   const float* __restrict__ codeN,
                                                   Partial* __restrict__ part) {
    __shared__ float Al[32][132];
    __shared__ float Bl[32][132];
    int bid = blockIdx.x;
    int ctile = bid >> 9, rtile = bid & 511;
    int tid = threadIdx.x, tx = tid & 15, ty = tid >> 4;
    float acc[8][8];
    #pragma unroll
    for (int i = 0; i < 8; ++i)
        #pragma unroll
        for (int j = 0; j < 8; ++j) acc[i][j] = 0.f;
    const float* Abase = A + (size_t)rtile * 128 * DIM;
    const float* Bbase = B + (size_t)ctile * 128 * DIM;
    for (int ds = 0; ds < 8; ++ds) {
        int d0 = ds * 32;
        __syncthreads();
        #pragma unroll
        for (int it = 0; it < 4; ++it) {
            int f = it * 256 + tid, row = f >> 3, dc = (f & 7) << 2;
            float4 va = *(const float4*)(Abase + (size_t)row * DIM + d0 + dc);
            Al[dc+0][row] = va.x; Al[dc+1][row] = va.y; Al[dc+2][row] = va.z; Al[dc+3][row] = va.w;
            float4 vb = *(const float4*)(Bbase + (size_t)row * DIM + d0 + dc);
            Bl[dc+0][row] = vb.x; Bl[dc+1][row] = vb.y; Bl[dc+2][row] = vb.z; Bl[dc+3][row] = vb.w;
        }
        __syncthreads();
        #pragma unroll 4
        for (int d = 0; d < 32; ++d) {
            const float4 a0 = *(const float4*)&Al[d][ty*8];
            const float4 a1 = *(const float4*)&Al[d][ty*8+4];
            const float4 b0 = *(const float4*)&Bl[d][tx*8];
            const float4 b1 = *(const float4*)&Bl[d][tx*8+4];
            float a[8] = {a0.x,a0.y,a0.z,a0.w,a1.x,a1.y,a1.z,a1.w};
            float b[8] = {b0.x,b0.y,b0.z,b0.w,b1.x,b1.y,b1.z,b1.w};
            #pragma unroll
            for (int i = 0; i < 8; ++i)
                #pragma unroll
                for (int j = 0; j < 8; ++j) acc[i][j] = fmaf(a[i], b[j], acc[i][j]);
        }
    }
    float rnv[8], cnv[8];
    #pragma unroll
    for (int i = 0; i < 8; ++i) rnv[i] = rowN[rtile*128 + ty*8 + i];
    #pragma unroll
    for (int j = 0; j < 8; ++j) cnv[j] = codeN[ctile*128 + tx*8 + j];
    #pragma unroll
    for (int i = 0; i < 8; ++i) {
        float bv = FLTMAX; int bi = 0x7fffffff;
        #pragma unroll
        for (int j = 0; j < 8; ++j) {
            float t1 = rnv[i] + cnv[j];
            float dv = t1 - 2.0f * acc[i][j];
            if (dv < bv) { bv = dv; bi = ctile*128 + tx*8 + j; }
        }
        #pragma unroll
        for (int m = 1; m <= 8; m <<= 1) {
            float ov = __shfl_xor(bv, m, 64); int oi = __shfl_xor(bi, m, 64);
            if (ov < bv || (ov == bv && oi < bi)) { bv = ov; bi = oi; }
        }
        if (tx == 0) {
            int row = rtile*128 + ty*8 + i;
            Partial p; p.v = bv; p.i = bi;
            part[(row << 3) + ctile] = p;
        }
    }
}

__global__ __launch_bounds__(256) void vq_reduce(const float* __restrict__ cb,
                                                 const Partial* __restrict__ part,
                                                 int* __restrict__ hist,
                                                 float* __restrict__ zq) {
    int row = (int)((blockIdx.x * 256u + threadIdx.x) >> 6);
    int lane = threadIdx.x & 63;
    float bv = FLTMAX; int bi = 0x7fffffff;
    if (lane < 8) { Partial p = part[(row << 3) + lane]; bv = p.v; bi = p.i; }
    #pragma unroll
    for (int m = 1; m <= 4; m <<= 1) {
        float ov = __shfl_xor(bv, m, 64); int oi = __shfl_xor(bi, m, 64);
        if (ov < bv || (ov == bv && oi < bi)) { bv = ov; bi = oi; }
    }
    bi = __shfl(bi, 0, 64);
    float4 v = ((const float4*)(cb + (size_t)bi * DIM))[lane];
    ((float4*)(zq + (size_t)row * DIM))[lane] = v;
    if (lane == 0) atomicAdd(&hist[bi], 1);
}

// ============ launch ============
extern "C" void kernel_launch(void* const* d_in, const int* in_sizes, int n_in,
                              void* d_out, int out_size, void* d_ws, size_t ws_size,
                              hipStream_t stream) {
    const float* z  = (const float*)d_in[0];
    const float* cb = (const float*)d_in[1];
    float* zq   = (float*)d_out;
    float* perp = zq + (size_t)N_ROWS * DIM;

    if (ws_size >= 76816384ULL) {
        ushort_t* A2  = (ushort_t*)d_ws;                          // [65536][512] bf16 hi|lo
        ushort_t* B2  = (ushort_t*)((char*)d_ws + 67108864);      // [1024][512]
        float*    rn  = (float*)((char*)d_ws + 68157440);
        float*    cn  = (float*)((char*)d_ws + 68419584);
        int*      hist= (int*)((char*)d_ws + 68423680);
        float4*   part= (float4*)((char*)d_ws + 68427776);        // [65536][8] top-2

        hipMemsetAsync(hist, 0, KCODES * sizeof(int), stream);
        vq_prep  <<<16640, 256, 0, stream>>>(z, cb, A2, B2, rn, cn);
        vq_gemm2 <<<4096,  256, 0, stream>>>(A2, B2, rn, cn, part);
        vq_refine<<<16384, 256, 0, stream>>>(z, cb, rn, cn, part, hist, zq);
        vq_perp  <<<1,     256, 0, stream>>>(hist, perp);
    } else {
        // R1 fallback
        float*   rowN  = (float*)d_ws;
        float*   codeN = rowN + N_ROWS;
        int*     hist  = (int*)(codeN + KCODES);
        Partial* part  = (Partial*)((char*)d_ws + 270336);
        hipMemsetAsync(hist, 0, KCODES * sizeof(int), stream);
        vq_norms  <<<16640, 256, 0, stream>>>(z, cb, rowN, codeN);
        vq_gemm_f32<<<4096, 256, 0, stream>>>(z, cb, rowN, codeN, part);
        vq_reduce <<<16384, 256, 0, stream>>>(cb, part, hist, zq);
        vq_perp   <<<1,     256, 0, stream>>>(hist, perp);
    }
}

// Round 4
// 296.630 us; speedup vs baseline: 1.8323x; 1.6782x over previous
//
#include <hip/hip_runtime.h>

#define N_ROWS 65536
#define DIM    256
#define KCODES 1024
#define FLTMAX 3.402823466e+38f
#define TAU    2e-4f

typedef short short8 __attribute__((ext_vector_type(8)));
typedef float f32x4  __attribute__((ext_vector_type(4)));
typedef unsigned short ushort_t;

__device__ __forceinline__ void gll16(const void* g, void* l) {
    __builtin_amdgcn_global_load_lds((const __attribute__((address_space(1))) void*)g,
                                     (__attribute__((address_space(3))) void*)l, 16, 0, 0);
}

__device__ __forceinline__ ushort_t bf16rn(float a) {
    unsigned ub = __float_as_uint(a);
    return (ushort_t)((ub + 0x7fffu + ((ub >> 16) & 1u)) >> 16);
}

// ============ kernel 1: norms + bf16 hi/lo split prep ============
__global__ __launch_bounds__(256) void vq_prep(const float* __restrict__ z,
                                               const float* __restrict__ cbk,
                                               ushort_t* __restrict__ A2,
                                               ushort_t* __restrict__ B2,
                                               float* __restrict__ rn,
                                               float* __restrict__ cn) {
    int gid = blockIdx.x * 256 + threadIdx.x;
    int row = gid >> 6;
    int l   = gid & 63;
    const float* src; ushort_t* dst; float* ndst;
    if (row < N_ROWS) { src = z   + (size_t)row * DIM; dst = A2 + (size_t)row * 512; ndst = rn + row; }
    else { int c = row - N_ROWS; src = cbk + (size_t)c * DIM; dst = B2 + (size_t)c * 512; ndst = cn + c; }
    float4 v = ((const float4*)src)[l];
    float s = v.x*v.x + v.y*v.y + v.z*v.z + v.w*v.w;
    #pragma unroll
    for (int m = 32; m; m >>= 1) s += __shfl_xor(s, m, 64);
    if (l == 0) *ndst = s;
    float a[4] = {v.x, v.y, v.z, v.w};
    ushort_t hi[4], lo[4];
    #pragma unroll
    for (int j = 0; j < 4; ++j) {
        hi[j] = bf16rn(a[j]);
        float r = a[j] - __uint_as_float(((unsigned)hi[j]) << 16);
        lo[j] = bf16rn(r);
    }
    ushort4 H = {hi[0], hi[1], hi[2], hi[3]};
    ushort4 L = {lo[0], lo[1], lo[2], lo[3]};
    *(ushort4*)(dst + l * 4)       = H;   // hi at k 0..255
    *(ushort4*)(dst + 256 + l * 4) = L;   // lo at k 256..511
}

// ============ kernel 2: bf16x3-split MFMA GEMM + fused top-2 argmin ============
__global__ __launch_bounds__(256) void vq_gemm2(const ushort_t* __restrict__ A2,
                                                const ushort_t* __restrict__ B2,
                                                const float* __restrict__ rn,
                                                const float* __restrict__ cn,
                                                float4* __restrict__ part) {
    __shared__ __align__(16) ushort_t As[128 * 64];
    __shared__ __align__(16) ushort_t Bs[128 * 64];

    int bid = blockIdx.x;
    int ctile = (bid >> 3) & 7;
    int rtile = (bid & 7) | ((bid >> 6) << 3);
    int tid = threadIdx.x;
    int wid = tid >> 6;
    int l   = tid & 63;
    int li  = l & 15, lg = l >> 4;
    int lrow  = l >> 3;
    int lcolb = ((l & 7) ^ lrow) << 4;
    int swz   = (l & 7) << 4;

    const size_t arow0 = (size_t)rtile * 128;
    const size_t ccol0 = (size_t)ctile * 128;

    f32x4 acc[2][8];
    #pragma unroll
    for (int rt = 0; rt < 2; ++rt)
        #pragma unroll
        for (int ct = 0; ct < 8; ++ct) acc[rt][ct] = (f32x4)0.f;

    int aO[2][2], bO[8][2];
    #pragma unroll
    for (int rt = 0; rt < 2; ++rt)
        #pragma unroll
        for (int ks = 0; ks < 2; ++ks)
            aO[rt][ks] = (wid*32 + rt*16 + li) * 128 + ((ks*64 + lg*16) ^ swz);
    #pragma unroll
    for (int ct = 0; ct < 8; ++ct)
        #pragma unroll
        for (int ks = 0; ks < 2; ++ks)
            bO[ct][ks] = (ct*16 + li) * 128 + ((ks*64 + lg*16) ^ swz);

    const char* gb; char* lb;
    int wrow0 = (wid & 1) * 64;
    if (wid < 2) { gb = (const char*)A2 + arow0 * 1024; lb = (char*)As; }
    else         { gb = (const char*)B2 + ccol0 * 1024; lb = (char*)Bs; }

    for (int s = 0; s < 12; ++s) {
        int aoff2 = (s < 8 ? (s & 3) * 64 : 256 + (s & 3) * 64) * 2;
        int boff2 = (s < 4 ? s * 64 : (s < 8 ? 256 + (s & 3) * 64 : (s & 3) * 64)) * 2;
        int off2 = (wid < 2) ? aoff2 : boff2;
        #pragma unroll
        for (int jj = 0; jj < 8; ++jj) {
            int r = wrow0 + jj * 8 + lrow;
            gll16(gb + (size_t)r * 1024 + off2 + lcolb,
                  lb + (wrow0 + jj * 8) * 128 + l * 16);
        }
        __syncthreads();
        #pragma unroll
        for (int ks = 0; ks < 2; ++ks) {
            short8 af[2];
            #pragma unroll
            for (int rt = 0; rt < 2; ++rt)
                af[rt] = *(const short8*)((const char*)As + aO[rt][ks]);
            #pragma unroll
            for (int ct = 0; ct < 8; ++ct) {
                short8 bf = *(const short8*)((const char*)Bs + bO[ct][ks]);
                acc[0][ct] = __builtin_amdgcn_mfma_f32_16x16x32_bf16(af[0], bf, acc[0][ct], 0, 0, 0);
                acc[1][ct] = __builtin_amdgcn_mfma_f32_16x16x32_bf16(af[1], bf, acc[1][ct], 0, 0, 0);
            }
        }
        __syncthreads();
    }

    float cnv[8];
    #pragma unroll
    for (int ct = 0; ct < 8; ++ct) cnv[ct] = cn[ccol0 + ct*16 + li];

    #pragma unroll
    for (int rt = 0; rt < 2; ++rt) {
        #pragma unroll
        for (int q = 0; q < 4; ++q) {
            int rowl = wid*32 + rt*16 + lg*4 + q;
            float rv = rn[arow0 + rowl];
            float v1 = FLTMAX; int i1 = 0x7fffffff;
            float v2 = FLTMAX; int i2 = 0x7fffffff;
            #pragma unroll
            for (int ct = 0; ct < 8; ++ct) {
                float dv = (rv + cnv[ct]) - 2.0f * acc[rt][ct][q];
                int  di = (int)ccol0 + ct*16 + li;
                bool b1 = (dv < v1) || (dv == v1 && di < i1);
                bool b2 = (dv < v2) || (dv == v2 && di < i2);
                float ov1 = v1; int oi1 = i1;
                if (b1)      { v1 = dv; i1 = di; v2 = ov1; i2 = oi1; }
                else if (b2) { v2 = dv; i2 = di; }
            }
            #pragma unroll
            for (int m = 1; m <= 8; m <<= 1) {
                float w1 = __shfl_xor(v1, m, 64); int j1 = __shfl_xor(i1, m, 64);
                float w2 = __shfl_xor(v2, m, 64); int j2 = __shfl_xor(i2, m, 64);
                bool first = (w1 < v1) || (w1 == v1 && j1 < i1);
                float nv1 = first ? w1 : v1; int ni1 = first ? j1 : i1;
                float c2v = first ? v1 : w1; int c2i = first ? i1 : j1;
                float av2 = first ? w2 : v2; int ai2 = first ? j2 : i2;
                bool s2 = (av2 < c2v) || (av2 == c2v && ai2 < c2i);
                v1 = nv1; i1 = ni1;
                v2 = s2 ? av2 : c2v; i2 = s2 ? ai2 : c2i;
            }
            if (li == 0) {
                float4 o;
                o.x = v1; o.y = __int_as_float(i1);
                o.z = v2; o.w = __int_as_float(i2);
                part[(arow0 + rowl) * 8 + ctile] = o;
            }
        }
    }
}

// ============ kernel 3: gap-gated exact refinement + gather + histogram ============
// Decision-identical to R2's vq_refine: if 2nd-best approx candidate is > TAU
// away, only one candidate would have passed R2's filter -> pick it directly
// (no z read). Else run the SAME sequential-d fp32 chain on the same filter set.
__global__ __launch_bounds__(256) void vq_refine2(const float* __restrict__ z,
                                                  const float* __restrict__ cbk,
                                                  const float* __restrict__ rn,
                                                  const float* __restrict__ cn,
                                                  const float4* __restrict__ part,
                                                  int* __restrict__ hist,
                                                  float* __restrict__ zq) {
    __shared__ float4 zl[4][64];
    int wid = threadIdx.x >> 6;
    int row = blockIdx.x * 4 + wid;
    int l   = threadIdx.x & 63;

    float vc = FLTMAX; int ic = 0x7fffffff;
    if (l < 16) {
        float4 P = part[(size_t)row * 8 + (l & 7)];
        if (l < 8) { vc = P.x; ic = __float_as_int(P.y); }
        else       { vc = P.z; ic = __float_as_int(P.w); }
    }
    // global top-2 over the 16 candidates (lanes 16..63 hold +inf)
    float v1 = vc; int i1 = ic; float v2 = FLTMAX; int i2 = 0x7fffffff;
    #pragma unroll
    for (int m = 1; m <= 8; m <<= 1) {
        float w1 = __shfl_xor(v1, m, 64); int j1 = __shfl_xor(i1, m, 64);
        float w2 = __shfl_xor(v2, m, 64); int j2 = __shfl_xor(i2, m, 64);
        bool first = (w1 < v1) || (w1 == v1 && j1 < i1);
        float nv1 = first ? w1 : v1; int ni1 = first ? j1 : i1;
        float c2v = first ? v1 : w1; int c2i = first ? i1 : j1;
        float av2 = first ? w2 : v2; int ai2 = first ? j2 : i2;
        bool s2 = (av2 < c2v) || (av2 == c2v && ai2 < c2i);
        v1 = nv1; i1 = ni1; v2 = s2 ? av2 : c2v; i2 = s2 ? ai2 : c2i;
    }
    v1 = __shfl(v1, 0, 64); i1 = __shfl(i1, 0, 64); v2 = __shfl(v2, 0, 64);

    int winner = i1;
    if (v2 - v1 <= TAU) {            // wave-uniform rare path (~1-3% of rows)
        zl[wid][l] = ((const float4*)(z + (size_t)row * DIM))[l];  // coalesced 1KB stage
        float dv = FLTMAX; int ci = 0x7fffffff;
        if (l < 16 && vc <= v1 + TAU) {
            const float4* cr = (const float4*)(cbk + (size_t)ic * DIM);
            float dot = 0.f;
            #pragma unroll 8
            for (int d4 = 0; d4 < 64; ++d4) {
                float4 c4 = cr[d4];
                float4 z4 = zl[wid][d4];   // broadcast read, compiler inserts lgkm wait
                dot = fmaf(z4.x, c4.x, dot); dot = fmaf(z4.y, c4.y, dot);
                dot = fmaf(z4.z, c4.z, dot); dot = fmaf(z4.w, c4.w, dot);
            }
            dv = (rn[row] + cn[ic]) - 2.0f * dot;   // same rounding as R1/R2-exact
            ci = ic;
        }
        #pragma unroll
        for (int m = 1; m <= 8; m <<= 1) {
            float ov = __shfl_xor(dv, m, 64); int oi = __shfl_xor(ci, m, 64);
            if (ov < dv || (ov == dv && oi < ci)) { dv = ov; ci = oi; }
        }
        winner = __shfl(ci, 0, 64);
    }

    float4 cv = ((const float4*)(cbk + (size_t)winner * DIM))[l];
    ((float4*)(zq + (size_t)row * DIM))[l] = cv;
    if (l == 0) atomicAdd(hist + winner, 1);
}

// ============ kernel 4: perplexity ============
__global__ __launch_bounds__(256) void vq_perp(const int* __restrict__ hist,
                                               float* __restrict__ out) {
    __shared__ float red[4];
    int tid = threadIdx.x;
    float s = 0.f;
    #pragma unroll
    for (int k = tid; k < KCODES; k += 256) {
        float avg = (float)hist[k] * (1.0f / 65536.0f);
        s += avg * logf(avg + 1e-10f);
    }
    #pragma unroll
    for (int m = 32; m; m >>= 1) s += __shfl_xor(s, m, 64);
    if ((tid & 63) == 0) red[tid >> 6] = s;
    __syncthreads();
    if (tid == 0) out[0] = expf(-(red[0] + red[1] + red[2] + red[3]));
}

// ============ launch ============
extern "C" void kernel_launch(void* const* d_in, const int* in_sizes, int n_in,
                              void* d_out, int out_size, void* d_ws, size_t ws_size,
                              hipStream_t stream) {
    const float* z  = (const float*)d_in[0];
    const float* cb = (const float*)d_in[1];
    float* zq   = (float*)d_out;
    float* perp = zq + (size_t)N_ROWS * DIM;

    ushort_t* A2  = (ushort_t*)d_ws;                          // [65536][512] bf16 hi|lo
    ushort_t* B2  = (ushort_t*)((char*)d_ws + 67108864);      // [1024][512]
    float*    rn  = (float*)((char*)d_ws + 68157440);
    float*    cn  = (float*)((char*)d_ws + 68419584);
    int*      hist= (int*)((char*)d_ws + 68423680);
    float4*   part= (float4*)((char*)d_ws + 68427776);        // [65536][8] top-2 per tile

    hipMemsetAsync(hist, 0, KCODES * sizeof(int), stream);
    vq_prep   <<<16640, 256, 0, stream>>>(z, cb, A2, B2, rn, cn);
    vq_gemm2  <<<4096,  256, 0, stream>>>(A2, B2, rn, cn, part);
    vq_refine2<<<16384, 256, 0, stream>>>(z, cb, rn, cn, part, hist, zq);
    vq_perp   <<<1,     256, 0, stream>>>(hist, perp);
}

// Round 5
// 236.715 us; speedup vs baseline: 2.2961x; 1.2531x over previous
//
#include <hip/hip_runtime.h>

#define N_ROWS 65536
#define DIM    256
#define KCODES 1024
#define FLTMAX 3.402823466e+38f
#define TAU    2e-4f

typedef _Float16 half8 __attribute__((ext_vector_type(8)));
typedef _Float16 half4_t __attribute__((ext_vector_type(4)));
typedef float f32x4  __attribute__((ext_vector_type(4)));
typedef unsigned short ushort_t;

__device__ __forceinline__ void gll16(const void* g, void* l) {
    __builtin_amdgcn_global_load_lds((const __attribute__((address_space(1))) void*)g,
                                     (__attribute__((address_space(3))) void*)l, 16, 0, 0);
}

// ============ kernel 1: norms + f16 conversion ============
__global__ __launch_bounds__(256) void vq_prep(const float* __restrict__ z,
                                               const float* __restrict__ cbk,
                                               _Float16* __restrict__ A2,
                                               _Float16* __restrict__ B2,
                                               float* __restrict__ rn,
                                               float* __restrict__ cn) {
    int gid = blockIdx.x * 256 + threadIdx.x;
    int row = gid >> 6;
    int l   = gid & 63;
    const float* src; _Float16* dst; float* ndst;
    if (row < N_ROWS) { src = z   + (size_t)row * DIM; dst = A2 + (size_t)row * DIM; ndst = rn + row; }
    else { int c = row - N_ROWS; src = cbk + (size_t)c * DIM; dst = B2 + (size_t)c * DIM; ndst = cn + c; }
    float4 v = ((const float4*)src)[l];
    float s = v.x*v.x + v.y*v.y + v.z*v.z + v.w*v.w;
    #pragma unroll
    for (int m = 32; m; m >>= 1) s += __shfl_xor(s, m, 64);
    if (l == 0) *ndst = s;
    half4_t h;
    h.x = (_Float16)v.x; h.y = (_Float16)v.y;
    h.z = (_Float16)v.z; h.w = (_Float16)v.w;
    *(half4_t*)(dst + l * 4) = h;
}

// ============ kernel 2: f16 MFMA GEMM (K'=256) + fused top-2 argmin ============
__global__ __launch_bounds__(256) void vq_gemm2(const _Float16* __restrict__ A2,
                                                const _Float16* __restrict__ B2,
                                                const float* __restrict__ rn,
                                                const float* __restrict__ cn,
                                                float4* __restrict__ part) {
    __shared__ __align__(16) _Float16 As[128 * 64];
    __shared__ __align__(16) _Float16 Bs[128 * 64];

    int bid = blockIdx.x;
    int ctile = (bid >> 3) & 7;
    int rtile = (bid & 7) | ((bid >> 6) << 3);
    int tid = threadIdx.x;
    int wid = tid >> 6;
    int l   = tid & 63;
    int li  = l & 15, lg = l >> 4;
    int lrow  = l >> 3;
    int lcolb = ((l & 7) ^ lrow) << 4;   // pre-swizzled global source byte col
    int swz   = (l & 7) << 4;            // read-side swizzle

    const size_t arow0 = (size_t)rtile * 128;
    const size_t ccol0 = (size_t)ctile * 128;

    f32x4 acc[2][8];
    #pragma unroll
    for (int rt = 0; rt < 2; ++rt)
        #pragma unroll
        for (int ct = 0; ct < 8; ++ct) acc[rt][ct] = (f32x4)0.f;

    int aO[2][2], bO[8][2];
    #pragma unroll
    for (int rt = 0; rt < 2; ++rt)
        #pragma unroll
        for (int ks = 0; ks < 2; ++ks)
            aO[rt][ks] = (wid*32 + rt*16 + li) * 128 + ((ks*64 + lg*16) ^ swz);
    #pragma unroll
    for (int ct = 0; ct < 8; ++ct)
        #pragma unroll
        for (int ks = 0; ks < 2; ++ks)
            bO[ct][ks] = (ct*16 + li) * 128 + ((ks*64 + lg*16) ^ swz);

    const char* gb; char* lb;
    int wrow0 = (wid & 1) * 64;
    if (wid < 2) { gb = (const char*)A2 + arow0 * 512; lb = (char*)As; }
    else         { gb = (const char*)B2 + ccol0 * 512; lb = (char*)Bs; }

    for (int s = 0; s < 4; ++s) {          // K'=256, BK=64 -> 4 stages
        int off2 = s * 128;                // byte offset within 512B row
        #pragma unroll
        for (int jj = 0; jj < 8; ++jj) {
            int r = wrow0 + jj * 8 + lrow;
            gll16(gb + (size_t)r * 512 + off2 + lcolb,
                  lb + (wrow0 + jj * 8) * 128 + l * 16);
        }
        __syncthreads();
        #pragma unroll
        for (int ks = 0; ks < 2; ++ks) {
            half8 af[2];
            #pragma unroll
            for (int rt = 0; rt < 2; ++rt)
                af[rt] = *(const half8*)((const char*)As + aO[rt][ks]);
            #pragma unroll
            for (int ct = 0; ct < 8; ++ct) {
                half8 bf = *(const half8*)((const char*)Bs + bO[ct][ks]);
                acc[0][ct] = __builtin_amdgcn_mfma_f32_16x16x32_f16(af[0], bf, acc[0][ct], 0, 0, 0);
                acc[1][ct] = __builtin_amdgcn_mfma_f32_16x16x32_f16(af[1], bf, acc[1][ct], 0, 0, 0);
            }
        }
        __syncthreads();
    }

    float cnv[8];
    #pragma unroll
    for (int ct = 0; ct < 8; ++ct) cnv[ct] = cn[ccol0 + ct*16 + li];

    #pragma unroll
    for (int rt = 0; rt < 2; ++rt) {
        #pragma unroll
        for (int q = 0; q < 4; ++q) {
            int rowl = wid*32 + rt*16 + lg*4 + q;
            float rv = rn[arow0 + rowl];
            float v1 = FLTMAX; int i1 = 0x7fffffff;
            float v2 = FLTMAX; int i2 = 0x7fffffff;
            #pragma unroll
            for (int ct = 0; ct < 8; ++ct) {
                float dv = (rv + cnv[ct]) - 2.0f * acc[rt][ct][q];
                int  di = (int)ccol0 + ct*16 + li;
                bool b1 = (dv < v1) || (dv == v1 && di < i1);
                bool b2 = (dv < v2) || (dv == v2 && di < i2);
                float ov1 = v1; int oi1 = i1;
                if (b1)      { v1 = dv; i1 = di; v2 = ov1; i2 = oi1; }
                else if (b2) { v2 = dv; i2 = di; }
            }
            #pragma unroll
            for (int m = 1; m <= 8; m <<= 1) {
                float w1 = __shfl_xor(v1, m, 64); int j1 = __shfl_xor(i1, m, 64);
                float w2 = __shfl_xor(v2, m, 64); int j2 = __shfl_xor(i2, m, 64);
                bool first = (w1 < v1) || (w1 == v1 && j1 < i1);
                float nv1 = first ? w1 : v1; int ni1 = first ? j1 : i1;
                float c2v = first ? v1 : w1; int c2i = first ? i1 : j1;
                float av2 = first ? w2 : v2; int ai2 = first ? j2 : i2;
                bool s2 = (av2 < c2v) || (av2 == c2v && ai2 < c2i);
                v1 = nv1; i1 = ni1;
                v2 = s2 ? av2 : c2v; i2 = s2 ? ai2 : c2i;
            }
            if (li == 0) {
                float4 o;
                o.x = v1; o.y = __int_as_float(i1);
                o.z = v2; o.w = __int_as_float(i2);
                part[(arow0 + rowl) * 8 + ctile] = o;
            }
        }
    }
}

// ============ kernel 3: gap-gated exact refinement + gather + histogram ============
__global__ __launch_bounds__(256) void vq_refine2(const float* __restrict__ z,
                                                  const float* __restrict__ cbk,
                                                  const float* __restrict__ rn,
                                                  const float* __restrict__ cn,
                                                  const float4* __restrict__ part,
                                                  int* __restrict__ hist,
                                                  float* __restrict__ zq) {
    __shared__ float4 zl[4][64];
    int wid = threadIdx.x >> 6;
    int row = blockIdx.x * 4 + wid;
    int l   = threadIdx.x & 63;

    float vc = FLTMAX; int ic = 0x7fffffff;
    if (l < 16) {
        float4 P = part[(size_t)row * 8 + (l & 7)];
        if (l < 8) { vc = P.x; ic = __float_as_int(P.y); }
        else       { vc = P.z; ic = __float_as_int(P.w); }
    }
    float v1 = vc; int i1 = ic; float v2 = FLTMAX; int i2 = 0x7fffffff;
    #pragma unroll
    for (int m = 1; m <= 8; m <<= 1) {
        float w1 = __shfl_xor(v1, m, 64); int j1 = __shfl_xor(i1, m, 64);
        float w2 = __shfl_xor(v2, m, 64); int j2 = __shfl_xor(i2, m, 64);
        bool first = (w1 < v1) || (w1 == v1 && j1 < i1);
        float nv1 = first ? w1 : v1; int ni1 = first ? j1 : i1;
        float c2v = first ? v1 : w1; int c2i = first ? i1 : j1;
        float av2 = first ? w2 : v2; int ai2 = first ? j2 : i2;
        bool s2 = (av2 < c2v) || (av2 == c2v && ai2 < c2i);
        v1 = nv1; i1 = ni1; v2 = s2 ? av2 : c2v; i2 = s2 ? ai2 : c2i;
    }
    v1 = __shfl(v1, 0, 64); i1 = __shfl(i1, 0, 64); v2 = __shfl(v2, 0, 64);

    int winner = i1;
    if (v2 - v1 <= TAU) {            // rare ambiguous path
        zl[wid][l] = ((const float4*)(z + (size_t)row * DIM))[l];
        float dv = FLTMAX; int ci = 0x7fffffff;
        if (l < 16 && vc <= v1 + TAU) {
            const float4* cr = (const float4*)(cbk + (size_t)ic * DIM);
            float dot = 0.f;
            #pragma unroll 8
            for (int d4 = 0; d4 < 64; ++d4) {
                float4 c4 = cr[d4];
                float4 z4 = zl[wid][d4];
                dot = fmaf(z4.x, c4.x, dot); dot = fmaf(z4.y, c4.y, dot);
                dot = fmaf(z4.z, c4.z, dot); dot = fmaf(z4.w, c4.w, dot);
            }
            dv = (rn[row] + cn[ic]) - 2.0f * dot;   // same rounding as proven-exact path
            ci = ic;
        }
        #pragma unroll
        for (int m = 1; m <= 8; m <<= 1) {
            float ov = __shfl_xor(dv, m, 64); int oi = __shfl_xor(ci, m, 64);
            if (ov < dv || (ov == dv && oi < ci)) { dv = ov; ci = oi; }
        }
        winner = __shfl(ci, 0, 64);
    }

    float4 cv = ((const float4*)(cbk + (size_t)winner * DIM))[l];
    ((float4*)(zq + (size_t)row * DIM))[l] = cv;
    if (l == 0) atomicAdd(hist + winner, 1);
}

// ============ kernel 4: perplexity ============
__global__ __launch_bounds__(256) void vq_perp(const int* __restrict__ hist,
                                               float* __restrict__ out) {
    __shared__ float red[4];
    int tid = threadIdx.x;
    float s = 0.f;
    #pragma unroll
    for (int k = tid; k < KCODES; k += 256) {
        float avg = (float)hist[k] * (1.0f / 65536.0f);
        s += avg * logf(avg + 1e-10f);
    }
    #pragma unroll
    for (int m = 32; m; m >>= 1) s += __shfl_xor(s, m, 64);
    if ((tid & 63) == 0) red[tid >> 6] = s;
    __syncthreads();
    if (tid == 0) out[0] = expf(-(red[0] + red[1] + red[2] + red[3]));
}

// ============ launch ============
extern "C" void kernel_launch(void* const* d_in, const int* in_sizes, int n_in,
                              void* d_out, int out_size, void* d_ws, size_t ws_size,
                              hipStream_t stream) {
    const float* z  = (const float*)d_in[0];
    const float* cb = (const float*)d_in[1];
    float* zq   = (float*)d_out;
    float* perp = zq + (size_t)N_ROWS * DIM;

    _Float16* A2  = (_Float16*)d_ws;                          // [65536][256] f16 (32 MB)
    _Float16* B2  = (_Float16*)((char*)d_ws + 33554432);      // [1024][256] f16 (512 KB)
    float*    rn  = (float*)((char*)d_ws + 34078720);         // 256 KB
    float*    cn  = (float*)((char*)d_ws + 34340864);         // 4 KB
    int*      hist= (int*)((char*)d_ws + 34344960);           // 4 KB
    float4*   part= (float4*)((char*)d_ws + 34349056);        // [65536][8] top-2 (8 MB)

    hipMemsetAsync(hist, 0, KCODES * sizeof(int), stream);
    vq_prep   <<<16640, 256, 0, stream>>>(z, cb, A2, B2, rn, cn);
    vq_gemm2  <<<4096,  256, 0, stream>>>(A2, B2, rn, cn, part);
    vq_refine2<<<16384, 256, 0, stream>>>(z, cb, rn, cn, part, hist, zq);
    vq_perp   <<<1,     256, 0, stream>>>(hist, perp);
}

// Round 6
// 221.030 us; speedup vs baseline: 2.4591x; 1.0710x over previous
//
#include <hip/hip_runtime.h>

#define N_ROWS 65536
#define DIM    256
#define KCODES 1024
#define FLTMAX 3.402823466e+38f
#define TAU    2e-4f

typedef _Float16 half8 __attribute__((ext_vector_type(8)));
typedef _Float16 half4_t __attribute__((ext_vector_type(4)));
typedef float f32x4  __attribute__((ext_vector_type(4)));

__device__ __forceinline__ void gll16(const void* g, void* l) {
    __builtin_amdgcn_global_load_lds((const __attribute__((address_space(1))) void*)g,
                                     (__attribute__((address_space(3))) void*)l, 16, 0, 0);
}

// ============ kernel 1: norms + f16 conversion ============
__global__ __launch_bounds__(256) void vq_prep(const float* __restrict__ z,
                                               const float* __restrict__ cbk,
                                               _Float16* __restrict__ A2,
                                               _Float16* __restrict__ B2,
                                               float* __restrict__ rn,
                                               float* __restrict__ cn) {
    int gid = blockIdx.x * 256 + threadIdx.x;
    int row = gid >> 6;
    int l   = gid & 63;
    const float* src; _Float16* dst; float* ndst;
    if (row < N_ROWS) { src = z   + (size_t)row * DIM; dst = A2 + (size_t)row * DIM; ndst = rn + row; }
    else { int c = row - N_ROWS; src = cbk + (size_t)c * DIM; dst = B2 + (size_t)c * DIM; ndst = cn + c; }
    float4 v = ((const float4*)src)[l];
    float s = v.x*v.x + v.y*v.y + v.z*v.z + v.w*v.w;
    #pragma unroll
    for (int m = 32; m; m >>= 1) s += __shfl_xor(s, m, 64);
    if (l == 0) *ndst = s;
    half4_t h;
    h.x = (_Float16)v.x; h.y = (_Float16)v.y;
    h.z = (_Float16)v.z; h.w = (_Float16)v.w;
    *(half4_t*)(dst + l * 4) = h;
}

// ============ kernel 2: f16 MFMA GEMM (K'=256) + u64 top-2 epilogue ============
__global__ __launch_bounds__(256) void vq_gemm2(const _Float16* __restrict__ A2,
                                                const _Float16* __restrict__ B2,
                                                const float* __restrict__ rn,
                                                const float* __restrict__ cn,
                                                ulonglong2* __restrict__ part) {
    __shared__ __align__(16) _Float16 As[2][8192];   // 2 x 16 KB
    __shared__ __align__(16) _Float16 Bs[2][8192];

    int bid = blockIdx.x;
    int ctile = (bid >> 3) & 7;
    int rtile = (bid & 7) | ((bid >> 6) << 3);
    int tid = threadIdx.x;
    int wid = tid >> 6;
    int l   = tid & 63;
    int li  = l & 15, lg = l >> 4;
    int lrow  = l >> 3;
    int lcolb = ((l & 7) ^ lrow) << 4;   // pre-swizzled global source byte col
    int swz   = (l & 7) << 4;            // read-side swizzle

    const size_t arow0 = (size_t)rtile * 128;
    const size_t ccol0 = (size_t)ctile * 128;

    // prefetch epilogue operands early (latency hides under K-loop)
    float cnv[8];
    #pragma unroll
    for (int ct = 0; ct < 8; ++ct) cnv[ct] = cn[ccol0 + ct*16 + li];
    float rv8[2][4];
    #pragma unroll
    for (int rt = 0; rt < 2; ++rt)
        #pragma unroll
        for (int q = 0; q < 4; ++q)
            rv8[rt][q] = rn[arow0 + wid*32 + rt*16 + lg*4 + q];

    f32x4 acc[2][8];
    #pragma unroll
    for (int rt = 0; rt < 2; ++rt)
        #pragma unroll
        for (int ct = 0; ct < 8; ++ct) acc[rt][ct] = (f32x4)0.f;

    int aO[2][2], bO[8][2];
    #pragma unroll
    for (int rt = 0; rt < 2; ++rt)
        #pragma unroll
        for (int ks = 0; ks < 2; ++ks)
            aO[rt][ks] = (wid*32 + rt*16 + li) * 128 + ((ks*64 + lg*16) ^ swz);
    #pragma unroll
    for (int ct = 0; ct < 8; ++ct)
        #pragma unroll
        for (int ks = 0; ks < 2; ++ks)
            bO[ct][ks] = (ct*16 + li) * 128 + ((ks*64 + lg*16) ^ swz);

    const char* gb; char* lb;
    int wrow0 = (wid & 1) * 64;
    if (wid < 2) { gb = (const char*)A2 + arow0 * 512; lb = (char*)As; }
    else         { gb = (const char*)B2 + ccol0 * 512; lb = (char*)Bs; }

    auto STAGE = [&](int s, int buf) {
        int off2 = s * 128;
        #pragma unroll
        for (int jj = 0; jj < 8; ++jj) {
            int r = wrow0 + jj * 8 + lrow;
            gll16(gb + (size_t)r * 512 + off2 + lcolb,
                  lb + buf * 16384 + (wrow0 + jj * 8) * 128 + l * 16);
        }
    };

    STAGE(0, 0);
    #pragma unroll
    for (int s = 0; s < 4; ++s) {
        int buf = s & 1;
        if (s < 3) {
            STAGE(s + 1, buf ^ 1);
            asm volatile("s_waitcnt vmcnt(8)" ::: "memory");   // prev stage landed, next in flight
        } else {
            asm volatile("s_waitcnt vmcnt(0)" ::: "memory");
        }
        __builtin_amdgcn_s_barrier();
        #pragma unroll
        for (int ks = 0; ks < 2; ++ks) {
            half8 af[2];
            #pragma unroll
            for (int rt = 0; rt < 2; ++rt)
                af[rt] = *(const half8*)((const char*)As + buf * 16384 + aO[rt][ks]);
            #pragma unroll
            for (int ct = 0; ct < 8; ++ct) {
                half8 bf = *(const half8*)((const char*)Bs + buf * 16384 + bO[ct][ks]);
                acc[0][ct] = __builtin_amdgcn_mfma_f32_16x16x32_f16(af[0], bf, acc[0][ct], 0, 0, 0);
                acc[1][ct] = __builtin_amdgcn_mfma_f32_16x16x32_f16(af[1], bf, acc[1][ct], 0, 0, 0);
            }
        }
        if (s < 3) __builtin_amdgcn_s_barrier();
    }

    // epilogue: dist = (rn + cn) - 2*dot, u64-packed top-2 per row over 128 codes.
    // dv >= 0 always (||x||^2 dominates) -> f32 bits order == float order;
    // low 32 = code idx -> u64 min == (dist, lowest-index tie) exactly.
    #pragma unroll
    for (int rt = 0; rt < 2; ++rt) {
        #pragma unroll
        for (int q = 0; q < 4; ++q) {
            int rowl = wid*32 + rt*16 + lg*4 + q;
            float rv = rv8[rt][q];
            unsigned long long v1 = ~0ull, v2 = ~0ull;
            #pragma unroll
            for (int ct = 0; ct < 8; ++ct) {
                float dvf = fmaf(-2.0f, acc[rt][ct][q], rv + cnv[ct]);
                unsigned long long x =
                    ((unsigned long long)__float_as_uint(dvf) << 32) |
                    (unsigned)(ccol0 + ct*16 + li);
                unsigned long long mn = x < v1 ? x : v1;
                unsigned long long mx = x < v1 ? v1 : x;
                v1 = mn;
                v2 = mx < v2 ? mx : v2;
            }
            #pragma unroll
            for (int m = 1; m <= 8; m <<= 1) {
                unsigned long long w1 = __shfl_xor(v1, m, 64);
                unsigned long long w2 = __shfl_xor(v2, m, 64);
                unsigned long long mn = v1 < w1 ? v1 : w1;
                unsigned long long mx = v1 < w1 ? w1 : v1;
                unsigned long long m2 = w2 < v2 ? w2 : v2;
                v1 = mn;
                v2 = mx < m2 ? mx : m2;
            }
            if (li == 0) {
                ulonglong2 o; o.x = v1; o.y = v2;
                part[(arow0 + rowl) * 8 + ctile] = o;
            }
        }
    }
}

// ============ kernel 3: gap-gated exact refinement + gather + histogram ============
__global__ __launch_bounds__(256) void vq_refine2(const float* __restrict__ z,
                                                  const float* __restrict__ cbk,
                                                  const float* __restrict__ rn,
                                                  const float* __restrict__ cn,
                                                  const ulonglong2* __restrict__ part,
                                                  int* __restrict__ hist,
                                                  float* __restrict__ zq) {
    __shared__ float4 zl[4][64];
    int wid = threadIdx.x >> 6;
    int row = blockIdx.x * 4 + wid;
    int l   = threadIdx.x & 63;

    unsigned long long vc = ~0ull;
    if (l < 16) {
        ulonglong2 P = part[(size_t)row * 8 + (l & 7)];
        vc = (l < 8) ? P.x : P.y;
    }
    // global top-2 over 16 candidates (u64 order == (dist, idx) order)
    unsigned long long v1 = vc, v2 = ~0ull;
    #pragma unroll
    for (int m = 1; m <= 8; m <<= 1) {
        unsigned long long w1 = __shfl_xor(v1, m, 64);
        unsigned long long w2 = __shfl_xor(v2, m, 64);
        unsigned long long mn = v1 < w1 ? v1 : w1;
        unsigned long long mx = v1 < w1 ? w1 : v1;
        unsigned long long m2 = w2 < v2 ? w2 : v2;
        v1 = mn;
        v2 = mx < m2 ? mx : m2;
    }
    v1 = __shfl(v1, 0, 64); v2 = __shfl(v2, 0, 64);
    float v1f = __uint_as_float((unsigned)(v1 >> 32));
    float v2f = __uint_as_float((unsigned)(v2 >> 32));

    int winner = (int)(v1 & 0xffffffffu);
    if (v2f - v1f <= TAU) {          // ambiguous: same exact-chain refine as R2/R4
        zl[wid][l] = ((const float4*)(z + (size_t)row * DIM))[l];
        float vcf = __uint_as_float((unsigned)(vc >> 32));
        int   ic  = (int)(vc & 0xffffffffu);
        unsigned long long e = ~0ull;
        if (l < 16 && vcf <= v1f + TAU) {
            const float4* cr = (const float4*)(cbk + (size_t)ic * DIM);
            float dot = 0.f;
            #pragma unroll 8
            for (int d4 = 0; d4 < 64; ++d4) {
                float4 c4 = cr[d4];
                float4 z4 = zl[wid][d4];
                dot = fmaf(z4.x, c4.x, dot); dot = fmaf(z4.y, c4.y, dot);
                dot = fmaf(z4.z, c4.z, dot); dot = fmaf(z4.w, c4.w, dot);
            }
            float dv = (rn[row] + cn[ic]) - 2.0f * dot;   // proven-exact rounding chain
            e = ((unsigned long long)__float_as_uint(dv) << 32) | (unsigned)ic;
        }
        #pragma unroll
        for (int m = 1; m <= 8; m <<= 1) {
            unsigned long long w = __shfl_xor(e, m, 64);
            e = w < e ? w : e;
        }
        winner = (int)(__shfl(e, 0, 64) & 0xffffffffu);
    }

    float4 cv = ((const float4*)(cbk + (size_t)winner * DIM))[l];
    ((float4*)(zq + (size_t)row * DIM))[l] = cv;
    if (l == 0) atomicAdd(hist + winner, 1);
}

// ============ kernel 4: perplexity ============
__global__ __launch_bounds__(256) void vq_perp(const int* __restrict__ hist,
                                               float* __restrict__ out) {
    __shared__ float red[4];
    int tid = threadIdx.x;
    float s = 0.f;
    #pragma unroll
    for (int k = tid; k < KCODES; k += 256) {
        float avg = (float)hist[k] * (1.0f / 65536.0f);
        s += avg * logf(avg + 1e-10f);
    }
    #pragma unroll
    for (int m = 32; m; m >>= 1) s += __shfl_xor(s, m, 64);
    if ((tid & 63) == 0) red[tid >> 6] = s;
    __syncthreads();
    if (tid == 0) out[0] = expf(-(red[0] + red[1] + red[2] + red[3]));
}

// ============ launch ============
extern "C" void kernel_launch(void* const* d_in, const int* in_sizes, int n_in,
                              void* d_out, int out_size, void* d_ws, size_t ws_size,
                              hipStream_t stream) {
    const float* z  = (const float*)d_in[0];
    const float* cb = (const float*)d_in[1];
    float* zq   = (float*)d_out;
    float* perp = zq + (size_t)N_ROWS * DIM;

    _Float16*   A2  = (_Float16*)d_ws;                        // [65536][256] f16 (32 MB)
    _Float16*   B2  = (_Float16*)((char*)d_ws + 33554432);    // [1024][256] f16
    float*      rn  = (float*)((char*)d_ws + 34078720);
    float*      cn  = (float*)((char*)d_ws + 34340864);
    int*        hist= (int*)((char*)d_ws + 34344960);
    ulonglong2* part= (ulonglong2*)((char*)d_ws + 34349056);  // [65536][8] top-2 (8 MB)

    hipMemsetAsync(hist, 0, KCODES * sizeof(int), stream);
    vq_prep   <<<16640, 256, 0, stream>>>(z, cb, A2, B2, rn, cn);
    vq_gemm2  <<<4096,  256, 0, stream>>>(A2, B2, rn, cn, part);
    vq_refine2<<<16384, 256, 0, stream>>>(z, cb, rn, cn, part, hist, zq);
    vq_perp   <<<1,     256, 0, stream>>>(hist, perp);
}